// Round 13
// baseline (77.604 us; speedup 1.0000x reference)
//
#include <hip/hip_runtime.h>
#include <hip/hip_bf16.h>

// out[d,l] = sum_n p[d,n] * gamma[d,n] * q[d,n]^l
// D=2048, N=16, L=4096. One block per d-row; 256 threads.
// Thread t produces float4 chunks {t, t+256, t+512, t+768} of the row:
//   l in [4*(t+256c), 4*(t+256c)+4) at chunk c, via geometric recurrence
//   pw[n] <- pw[n]*q[n] per l, and pw[n] <- pw[n]*q[n]^(1024-4) between chunks.
//
// Profile decision rule (first real bench): dur>12us & VALUBusy high ->
// seed/recurrence cost, enlarge per-thread chunk; dur>12us & all low ->
// occupancy/launch overhead.

#define EMA_N 16
#define BLOCK 256

// Native clang vector type: __builtin_nontemporal_store rejects HIP's
// float4 class (round-6 compile error) but accepts ext_vector_type.
typedef float f32x4 __attribute__((ext_vector_type(4)));

__global__ __launch_bounds__(BLOCK) void ema_filter_kernel(
    const float* __restrict__ p,
    const float* __restrict__ q,
    const float* __restrict__ gamma,
    float* __restrict__ out,
    int L)
{
    const int d = blockIdx.x;
    const int t = threadIdx.x;

    __shared__ float  s_q[EMA_N];      // q
    __shared__ float  s_coef[EMA_N];   // p * gamma
    __shared__ float  s_qjump[EMA_N];  // q^(4*BLOCK - 4)
    __shared__ double s_logq[EMA_N];   // log2(q), f64 so l0*log2(q) is accurate

    if (t < EMA_N) {
        const size_t base = (size_t)d * EMA_N + t;
        const float qn = q[base];
        const double lg = log2((double)qn);
        s_q[t]     = qn;
        s_coef[t]  = p[base] * gamma[base];
        s_logq[t]  = lg;
        s_qjump[t] = (float)exp2((double)(4 * BLOCK - 4) * lg);
    }
    __syncthreads();

    float qv[EMA_N], pw[EMA_N], qj[EMA_N];
    const double fl0 = (double)(4 * t);
    #pragma unroll
    for (int n = 0; n < EMA_N; ++n) {
        qv[n] = s_q[n];
        qj[n] = s_qjump[n];
        // seed: (p*gamma) * q^{4t}. exp2f -> single v_exp_f32 (<=1 ulp); the
        // exponent product in f64 keeps l0*log2(q) accurate for all l0.
        pw[n] = s_coef[n] * exp2f((float)(fl0 * s_logq[n]));
    }

    f32x4* orow = reinterpret_cast<f32x4*>(out + (size_t)d * L);
    const int nchunk = L / (4 * BLOCK);            // 4 for L=4096
    int cidx = t;
    for (int c = 0; c < nchunk; ++c) {
        float r0, r1, r2, r3;          // named scalars: guaranteed registers
        {
            float acc0 = 0.f, acc1 = 0.f;
            #pragma unroll
            for (int n = 0; n < EMA_N; n += 2) {
                acc0 += pw[n];     pw[n]     *= qv[n];
                acc1 += pw[n + 1]; pw[n + 1] *= qv[n + 1];
            }
            r0 = acc0 + acc1;
        }
        {
            float acc0 = 0.f, acc1 = 0.f;
            #pragma unroll
            for (int n = 0; n < EMA_N; n += 2) {
                acc0 += pw[n];     pw[n]     *= qv[n];
                acc1 += pw[n + 1]; pw[n + 1] *= qv[n + 1];
            }
            r1 = acc0 + acc1;
        }
        {
            float acc0 = 0.f, acc1 = 0.f;
            #pragma unroll
            for (int n = 0; n < EMA_N; n += 2) {
                acc0 += pw[n];     pw[n]     *= qv[n];
                acc1 += pw[n + 1]; pw[n + 1] *= qv[n + 1];
            }
            r2 = acc0 + acc1;
        }
        {
            float acc0 = 0.f, acc1 = 0.f;
            #pragma unroll
            for (int n = 0; n < EMA_N; n += 2) {
                acc0 += pw[n];     pw[n]     *= qv[n];
                acc1 += pw[n + 1]; pw[n + 1] *= qv[n + 1];
            }
            r3 = acc0 + acc1;
        }
        // Write-once stream: non-temporal to keep L2 for the (tiny) inputs.
        f32x4 r = { r0, r1, r2, r3 };
        __builtin_nontemporal_store(r, &orow[cidx]);
        cidx += BLOCK;
        if (c + 1 < nchunk) {
            #pragma unroll
            for (int n = 0; n < EMA_N; ++n) pw[n] *= qj[n];
        }
    }
}

extern "C" void kernel_launch(void* const* d_in, const int* in_sizes, int n_in,
                              void* d_out, int out_size, void* d_ws, size_t ws_size,
                              hipStream_t stream) {
    const float* p     = (const float*)d_in[0];   // (D, N, 1)
    const float* q     = (const float*)d_in[1];   // (D, N, 1)
    const float* gamma = (const float*)d_in[2];   // (D, N)
    // d_in[3] is `length`; L derived from out_size instead.

    const int D = in_sizes[2] / EMA_N;            // 2048
    const int L = out_size / D;                   // 4096

    ema_filter_kernel<<<D, BLOCK, 0, stream>>>(p, q, gamma, (float*)d_out, L);
}

// Round 19
// 76.790 us; speedup vs baseline: 1.0106x; 1.0106x over previous
//
#include <hip/hip_runtime.h>
#include <hip/hip_bf16.h>

// out[d,l] = sum_n p[d,n] * gamma[d,n] * q[d,n]^l
// D=2048, N=16, L=4096. One block per d-row; 256 threads.
// Thread t produces float4 chunks {t, t+256, t+512, t+768} of the row:
//   l in [4*(t+256c), 4*(t+256c)+4) at chunk c, via geometric recurrence
//   pw[n] <- pw[n]*q[n] per l, and pw[n] <- pw[n]*q[n]^(1024-4) between chunks.
//
// R13 post-mortem: bench dur 77.6us includes harness re-poison fills
// (256MiB ws fill = 44us @ 6.1TB/s + 32MiB out fill); ema_filter_kernel
// itself < 43us (absent from top-5), est. 20-28us — still 4-5x the 5.6us
// write floor. R14 single-variable test: drop nontemporal store (suspect:
// nt flag bypasses L2 write-combining -> degraded store BW; fills without
// nt hit 6.1 TB/s).

#define EMA_N 16
#define BLOCK 256

typedef float f32x4 __attribute__((ext_vector_type(4)));

__global__ __launch_bounds__(BLOCK) void ema_filter_kernel(
    const float* __restrict__ p,
    const float* __restrict__ q,
    const float* __restrict__ gamma,
    float* __restrict__ out,
    int L)
{
    const int d = blockIdx.x;
    const int t = threadIdx.x;

    __shared__ float  s_q[EMA_N];      // q
    __shared__ float  s_coef[EMA_N];   // p * gamma
    __shared__ float  s_qjump[EMA_N];  // q^(4*BLOCK - 4)
    __shared__ double s_logq[EMA_N];   // log2(q), f64 so l0*log2(q) is accurate

    if (t < EMA_N) {
        const size_t base = (size_t)d * EMA_N + t;
        const float qn = q[base];
        const double lg = log2((double)qn);
        s_q[t]     = qn;
        s_coef[t]  = p[base] * gamma[base];
        s_logq[t]  = lg;
        s_qjump[t] = (float)exp2((double)(4 * BLOCK - 4) * lg);
    }
    __syncthreads();

    float qv[EMA_N], pw[EMA_N], qj[EMA_N];
    const double fl0 = (double)(4 * t);
    #pragma unroll
    for (int n = 0; n < EMA_N; ++n) {
        qv[n] = s_q[n];
        qj[n] = s_qjump[n];
        // seed: (p*gamma) * q^{4t}. exp2f -> single v_exp_f32 (<=1 ulp); the
        // exponent product in f64 keeps l0*log2(q) accurate for all l0.
        pw[n] = s_coef[n] * exp2f((float)(fl0 * s_logq[n]));
    }

    f32x4* orow = reinterpret_cast<f32x4*>(out + (size_t)d * L);
    const int nchunk = L / (4 * BLOCK);            // 4 for L=4096
    int cidx = t;
    for (int c = 0; c < nchunk; ++c) {
        float r0, r1, r2, r3;          // named scalars: guaranteed registers
        {
            float acc0 = 0.f, acc1 = 0.f;
            #pragma unroll
            for (int n = 0; n < EMA_N; n += 2) {
                acc0 += pw[n];     pw[n]     *= qv[n];
                acc1 += pw[n + 1]; pw[n + 1] *= qv[n + 1];
            }
            r0 = acc0 + acc1;
        }
        {
            float acc0 = 0.f, acc1 = 0.f;
            #pragma unroll
            for (int n = 0; n < EMA_N; n += 2) {
                acc0 += pw[n];     pw[n]     *= qv[n];
                acc1 += pw[n + 1]; pw[n + 1] *= qv[n + 1];
            }
            r1 = acc0 + acc1;
        }
        {
            float acc0 = 0.f, acc1 = 0.f;
            #pragma unroll
            for (int n = 0; n < EMA_N; n += 2) {
                acc0 += pw[n];     pw[n]     *= qv[n];
                acc1 += pw[n + 1]; pw[n + 1] *= qv[n + 1];
            }
            r2 = acc0 + acc1;
        }
        {
            float acc0 = 0.f, acc1 = 0.f;
            #pragma unroll
            for (int n = 0; n < EMA_N; n += 2) {
                acc0 += pw[n];     pw[n]     *= qv[n];
                acc1 += pw[n + 1]; pw[n + 1] *= qv[n + 1];
            }
            r3 = acc0 + acc1;
        }
        // R14: plain (cached, write-back) vector store — NT removed.
        f32x4 r = { r0, r1, r2, r3 };
        orow[cidx] = r;
        cidx += BLOCK;
        if (c + 1 < nchunk) {
            #pragma unroll
            for (int n = 0; n < EMA_N; ++n) pw[n] *= qj[n];
        }
    }
}

extern "C" void kernel_launch(void* const* d_in, const int* in_sizes, int n_in,
                              void* d_out, int out_size, void* d_ws, size_t ws_size,
                              hipStream_t stream) {
    const float* p     = (const float*)d_in[0];   // (D, N, 1)
    const float* q     = (const float*)d_in[1];   // (D, N, 1)
    const float* gamma = (const float*)d_in[2];   // (D, N)
    // d_in[3] is `length`; L derived from out_size instead.

    const int D = in_sizes[2] / EMA_N;            // 2048
    const int L = out_size / D;                   // 4096

    ema_filter_kernel<<<D, BLOCK, 0, stream>>>(p, q, gamma, (float*)d_out, L);
}